// Round 14
// baseline (452.528 us; speedup 1.0000x reference)
//
#include <hip/hip_runtime.h>

// ---------- types ----------
typedef __attribute__((ext_vector_type(8))) short short8;
typedef __attribute__((ext_vector_type(8))) unsigned short ushort8;
typedef __attribute__((ext_vector_type(4))) float f32x4;

__device__ __forceinline__ float b2f(short s) {
    unsigned u = ((unsigned)(unsigned short)s) << 16;
    return __builtin_bit_cast(float, u);
}
__device__ __forceinline__ unsigned short f2b(float f) {
    unsigned u = __builtin_bit_cast(unsigned, f);
    u += 0x7fffu + ((u >> 16) & 1u);   // round-to-nearest-even
    return (unsigned short)(u >> 16);
}

// global -> LDS async copy, 16B per lane (wave-uniform LDS base + lane*16)
__device__ __forceinline__ void gload_lds16(const void* gptr, void* ldsptr) {
    typedef __attribute__((address_space(1))) const void gv_t;
    typedef __attribute__((address_space(3))) void lv_t;
    gv_t* g = reinterpret_cast<gv_t*>(reinterpret_cast<unsigned long long>(gptr));
    lv_t* l = reinterpret_cast<lv_t*>((unsigned int)reinterpret_cast<unsigned long long>(ldsptr));
    __builtin_amdgcn_global_load_lds(g, l, 16, 0, 0);
}

// ---------- one-shot fp32->bf16 conversion for all inputs + bias concat ----------
__global__ __launch_bounds__(256) void cvt_all(const float* __restrict__ x,
                                               const float* __restrict__ Wq,
                                               const float* __restrict__ Wk,
                                               const float* __restrict__ Wv,
                                               const float* __restrict__ Wo,
                                               const float* __restrict__ bq,
                                               const float* __restrict__ bk,
                                               const float* __restrict__ bv,
                                               unsigned short* __restrict__ xb,
                                               unsigned short* __restrict__ wqkv,
                                               unsigned short* __restrict__ wo,
                                               float* __restrict__ bqkv) {
    const int bid = blockIdx.x;
    const float* src;
    unsigned short* dst;
    int base8;
    if (bid < 16384)      { src = x;  dst = xb;              base8 = bid; }
    else if (bid < 16896) { src = Wq; dst = wqkv;            base8 = bid - 16384; }
    else if (bid < 17408) { src = Wk; dst = wqkv + 1048576;  base8 = bid - 16896; }
    else if (bid < 17920) { src = Wv; dst = wqkv + 2097152;  base8 = bid - 17408; }
    else if (bid < 18432) { src = Wo; dst = wo;              base8 = bid - 17920; }
    else {
        const int i = threadIdx.x;
#pragma unroll
        for (int r = 0; r < 12; ++r) {   // 3072 floats
            int j = r * 256 + i;
            float v = (j < 1024) ? bq[j] : (j < 2048 ? bk[j - 1024] : bv[j - 2048]);
            bqkv[j] = v;
        }
        return;
    }
    const size_t i8 = (size_t)base8 * 256 + threadIdx.x;
    const float4* p = (const float4*)src + i8 * 2;
    float4 a = p[0], b = p[1];
    ushort8 o;
    o[0] = f2b(a.x); o[1] = f2b(a.y); o[2] = f2b(a.z); o[3] = f2b(a.w);
    o[4] = f2b(b.x); o[5] = f2b(b.y); o[6] = f2b(b.z); o[7] = f2b(b.w);
    *(ushort8*)(dst + i8 * 8) = o;
}

// ---------- GEMM m97-style: 128x128 tile, BK=64, 4 waves, 32 KiB static LDS ----------
// (R10/R13-proven: 917 TF, MfmaUtil 42%, conflicts 0, ~3 blocks/CU.)
template <bool OUT_BF16>
__global__ void gemm128(const short* __restrict__ A,   // [M,K] bf16
                        const short* __restrict__ B,   // [N,K] bf16
                        const float* __restrict__ bias,// [N]
                        unsigned short* __restrict__ Cb,
                        float* __restrict__ Cf,
                        int M, int N, int K) {
    __shared__ short As[128][64];
    __shared__ short Bs[128][64];

    const int lane = threadIdx.x & 63;
    const int wave = threadIdx.x >> 6;       // 0..3
    const int wr = wave >> 1, wc = wave & 1;

    const int nwg = gridDim.x;
    const int bid = blockIdx.x;
    const int swz = (bid & 7) * (nwg >> 3) + (bid >> 3);
    const int ncol = N >> 7;
    const int trow = swz / ncol, tcol = swz % ncol;

    const int srow = wave * 8 + (lane >> 3);
    const int scol = ((lane & 7) ^ (lane >> 3)) * 8;
    const short* Abase = A + (size_t)(trow * 128 + srow) * K + scol;
    const short* Bbase = B + (size_t)(tcol * 128 + srow) * K + scol;
    short* AsBase = &As[wave * 8][0];
    short* BsBase = &Bs[wave * 8][0];

    const int rl = lane & 15;
    const int g0 = ((lane >> 4) ^ (lane & 7)) * 8;       // ks0 phys granule (shorts)
    const int g1 = ((4 + (lane >> 4)) ^ (lane & 7)) * 8; // ks1 phys granule

    f32x4 acc[4][4] = {};

    for (int kt = 0; kt < K; kt += 64) {
#pragma unroll
        for (int i = 0; i < 4; ++i) {
            gload_lds16(Abase + kt + (size_t)i * 32 * K, AsBase + i * 32 * 64);
            gload_lds16(Bbase + kt + (size_t)i * 32 * K, BsBase + i * 32 * 64);
        }
        __syncthreads();
#pragma unroll
        for (int ks = 0; ks < 2; ++ks) {
            const int g = ks ? g1 : g0;
            short8 af[4], bfr[4];
#pragma unroll
            for (int m = 0; m < 4; ++m)
                af[m] = *(const short8*)&As[wr * 64 + m * 16 + rl][g];
#pragma unroll
            for (int n = 0; n < 4; ++n)
                bfr[n] = *(const short8*)&Bs[wc * 64 + n * 16 + rl][g];
#pragma unroll
            for (int m = 0; m < 4; ++m)
#pragma unroll
                for (int n = 0; n < 4; ++n)
                    acc[m][n] = __builtin_amdgcn_mfma_f32_16x16x32_bf16(af[m], bfr[n], acc[m][n], 0, 0, 0);
        }
        __syncthreads();
    }

    const int crow0 = trow * 128 + wr * 64 + (lane >> 4) * 4;
    const int ccol0 = tcol * 128 + wc * 64 + rl;
#pragma unroll
    for (int n = 0; n < 4; ++n) {
        const int col = ccol0 + n * 16;
        const float bv = bias[col];
#pragma unroll
        for (int m = 0; m < 4; ++m) {
            const int row0 = crow0 + m * 16;
#pragma unroll
            for (int r = 0; r < 4; ++r) {
                float val = acc[m][n][r] + bv;
                if (OUT_BF16) Cb[(size_t)(row0 + r) * N + col] = f2b(val);
                else          Cf[(size_t)(row0 + r) * N + col] = val;
            }
        }
    }
}

// ---------- per-token cross-head attention: K staged in LDS, V from global ----------
// block = 256 thr / 16 tokens. K-only staging halves LDS to 32 KB -> 4-5
// blocks/CU (vs 2 with K+V), doubling latency-hiding occupancy. V reads come
// straight from y1 (192 MB < 256 MB L3-resident; per wave instr = 4 distinct
// 16B lines broadcast to 16 lanes each, high MLP under the PV FMA work).
// K rotation (col + 8*row mod 1024): per wave instr the 4 tokens' 16B reads
// land on 4-bank-spaced groups -> 16 distinct banks, broadcast -> conflict-free.
__global__ __launch_bounds__(256) void attn2b(const short* __restrict__ qkv,
                                              short* __restrict__ out) {
    __shared__ short kv[16 * 1024];   // 32 KiB, K rows only
    const int tid = threadIdx.x;
    const size_t t0 = (size_t)blockIdx.x * 16;

    // flat staging: 2048 chunks of 8 shorts (16 rows x 128 chunks), 8 iters
#pragma unroll
    for (int i = 0; i < 8; ++i) {
        const int cid = i * 256 + tid;
        const int row = cid >> 7, col = cid & 127;
        short8 v = *(const short8*)(qkv + (t0 + row) * 3072 + 1024 + col * 8);
        *(short8*)(kv + row * 1024 + ((col * 8 + row * 8) & 1023)) = v;
    }
    __syncthreads();

    const int t = tid >> 4, h = tid & 15;
    const int rot = t * 8;
    const short* kt = kv + t * 1024;
    const short* q  = qkv + (t0 + t) * 3072 + h * 64;
    const short* vb = qkv + (t0 + t) * 3072 + 2048;

    float qf[64];
#pragma unroll
    for (int j = 0; j < 8; ++j) {
        short8 qv = *(const short8*)(q + j * 8);
#pragma unroll
        for (int i = 0; i < 8; ++i) qf[j * 8 + i] = b2f(qv[i]);
    }

    float s[16];
    float mx = -1e30f;
#pragma unroll
    for (int g = 0; g < 16; ++g) {
        float a = 0.f;
#pragma unroll
        for (int j = 0; j < 8; ++j) {
            short8 kvv = *(const short8*)(kt + ((g * 64 + j * 8 + rot) & 1023));
#pragma unroll
            for (int i = 0; i < 8; ++i) a += qf[j * 8 + i] * b2f(kvv[i]);
        }
        s[g] = a * 0.125f;   // scale = 1/sqrt(64)
        mx = fmaxf(mx, s[g]);
    }
    float den = 0.f;
#pragma unroll
    for (int g = 0; g < 16; ++g) { s[g] = __expf(s[g] - mx); den += s[g]; }
    float inv = 1.f / den;

#pragma unroll
    for (int j = 0; j < 8; ++j) {
        float o[8] = {0.f, 0.f, 0.f, 0.f, 0.f, 0.f, 0.f, 0.f};
#pragma unroll
        for (int g = 0; g < 16; ++g) {
            short8 vv = *(const short8*)(vb + g * 64 + j * 8);   // global, L3-hot
            float w = s[g];
#pragma unroll
            for (int i = 0; i < 8; ++i) o[i] += w * b2f(vv[i]);
        }
        short8 ov;
#pragma unroll
        for (int i = 0; i < 8; ++i) ov[i] = (short)f2b(o[i] * inv);
        *(short8*)(out + (t0 + t) * 1024 + h * 64 + j * 8) = ov;
    }
}

// ---------- launch ----------
extern "C" void kernel_launch(void* const* d_in, const int* in_sizes, int n_in,
                              void* d_out, int out_size, void* d_ws, size_t ws_size,
                              hipStream_t stream) {
    const float* x  = (const float*)d_in[0];
    const float* Wq = (const float*)d_in[1];
    const float* bq = (const float*)d_in[2];
    const float* Wk = (const float*)d_in[3];
    const float* bk = (const float*)d_in[4];
    const float* Wv = (const float*)d_in[5];
    const float* bv = (const float*)d_in[6];
    const float* Wo = (const float*)d_in[7];
    const float* bo = (const float*)d_in[8];
    float* out = (float*)d_out;

    const int N = 32768, E = 1024;

    char* ws = (char*)d_ws;
    size_t off = 0;
    short* xb = (short*)(ws + off);         off += (size_t)N * E * 2;
    short* wqkv = (short*)(ws + off);       off += (size_t)3 * E * E * 2;
    short* wo = (short*)(ws + off);         off += (size_t)E * E * 2;
    float* bqkv = (float*)(ws + off);       off += (size_t)3 * E * 4;
    off = (off + 255) & ~(size_t)255;
    short* y1 = (short*)(ws + off);         off += (size_t)N * 3 * E * 2;
    short* ao = xb;  // reuse xb: dead after GEMM1

    // 1) fused conversion (single launch)
    cvt_all<<<dim3(18433), dim3(256), 0, stream>>>(
        x, Wq, Wk, Wv, Wo, bq, bk, bv,
        (unsigned short*)xb, (unsigned short*)wqkv, (unsigned short*)wo, bqkv);

    // 2) QKV projection: grid (32768/128)*(3072/128) = 256*24 = 6144 (%8==0)
    gemm128<true><<<dim3((N / 128) * (3 * E / 128)), dim3(256), 0, stream>>>(
        xb, wqkv, bqkv, (unsigned short*)y1, nullptr, N, 3 * E, E);

    // 3) per-token attention, K-staged / V-global: 2048 blocks x 256 thr
    attn2b<<<dim3(N / 16), dim3(256), 0, stream>>>(y1, ao);

    // 4) output projection: grid 256*8 = 2048 (%8==0)
    gemm128<false><<<dim3((N / 128) * (E / 128)), dim3(256), 0, stream>>>(
        ao, wo, bo, nullptr, out, N, E, E);
}

// Round 15
// 424.228 us; speedup vs baseline: 1.0667x; 1.0667x over previous
//
#include <hip/hip_runtime.h>

// ---------- types ----------
typedef __attribute__((ext_vector_type(8))) short short8;
typedef __attribute__((ext_vector_type(8))) unsigned short ushort8;
typedef __attribute__((ext_vector_type(4))) float f32x4;

__device__ __forceinline__ float b2f(short s) {
    unsigned u = ((unsigned)(unsigned short)s) << 16;
    return __builtin_bit_cast(float, u);
}
__device__ __forceinline__ unsigned short f2b(float f) {
    unsigned u = __builtin_bit_cast(unsigned, f);
    u += 0x7fffu + ((u >> 16) & 1u);   // round-to-nearest-even
    return (unsigned short)(u >> 16);
}

// global -> LDS async copy, 16B per lane (wave-uniform LDS base + lane*16)
__device__ __forceinline__ void gload_lds16(const void* gptr, void* ldsptr) {
    typedef __attribute__((address_space(1))) const void gv_t;
    typedef __attribute__((address_space(3))) void lv_t;
    gv_t* g = reinterpret_cast<gv_t*>(reinterpret_cast<unsigned long long>(gptr));
    lv_t* l = reinterpret_cast<lv_t*>((unsigned int)reinterpret_cast<unsigned long long>(ldsptr));
    __builtin_amdgcn_global_load_lds(g, l, 16, 0, 0);
}

// ---------- one-shot fp32->bf16 conversion for all inputs + bias concat ----------
__global__ __launch_bounds__(256) void cvt_all(const float* __restrict__ x,
                                               const float* __restrict__ Wq,
                                               const float* __restrict__ Wk,
                                               const float* __restrict__ Wv,
                                               const float* __restrict__ Wo,
                                               const float* __restrict__ bq,
                                               const float* __restrict__ bk,
                                               const float* __restrict__ bv,
                                               unsigned short* __restrict__ xb,
                                               unsigned short* __restrict__ wqkv,
                                               unsigned short* __restrict__ wo,
                                               float* __restrict__ bqkv) {
    const int bid = blockIdx.x;
    const float* src;
    unsigned short* dst;
    int base8;
    if (bid < 16384)      { src = x;  dst = xb;              base8 = bid; }
    else if (bid < 16896) { src = Wq; dst = wqkv;            base8 = bid - 16384; }
    else if (bid < 17408) { src = Wk; dst = wqkv + 1048576;  base8 = bid - 16896; }
    else if (bid < 17920) { src = Wv; dst = wqkv + 2097152;  base8 = bid - 17408; }
    else if (bid < 18432) { src = Wo; dst = wo;              base8 = bid - 17920; }
    else {
        const int i = threadIdx.x;
#pragma unroll
        for (int r = 0; r < 12; ++r) {   // 3072 floats
            int j = r * 256 + i;
            float v = (j < 1024) ? bq[j] : (j < 2048 ? bk[j - 1024] : bv[j - 2048]);
            bqkv[j] = v;
        }
        return;
    }
    const size_t i8 = (size_t)base8 * 256 + threadIdx.x;
    const float4* p = (const float4*)src + i8 * 2;
    float4 a = p[0], b = p[1];
    ushort8 o;
    o[0] = f2b(a.x); o[1] = f2b(a.y); o[2] = f2b(a.z); o[3] = f2b(a.w);
    o[4] = f2b(b.x); o[5] = f2b(b.y); o[6] = f2b(b.z); o[7] = f2b(b.w);
    *(ushort8*)(dst + i8 * 8) = o;
}

// ---------- GEMM m97-style: 128x128 tile, BK=64, 4 waves, 32 KiB static LDS ----------
// (R10/R13-proven: 917 TF, MfmaUtil 42%, conflicts 0, ~3 blocks/CU.)
// Multi-block co-residency is the overlap mechanism (m97/m114): while one
// block drains at its barrier, other blocks' waves feed the matrix pipe.
// Granule-XOR swizzle: stage source supplies logical granule (l&7)^(l>>3);
// reads use phys = g ^ (lane&7). XCD-aware block swizzle (grid % 8 == 0).
template <bool OUT_BF16>
__global__ void gemm128(const short* __restrict__ A,   // [M,K] bf16
                        const short* __restrict__ B,   // [N,K] bf16
                        const float* __restrict__ bias,// [N]
                        unsigned short* __restrict__ Cb,
                        float* __restrict__ Cf,
                        int M, int N, int K) {
    __shared__ short As[128][64];
    __shared__ short Bs[128][64];

    const int lane = threadIdx.x & 63;
    const int wave = threadIdx.x >> 6;       // 0..3
    const int wr = wave >> 1, wc = wave & 1;

    const int nwg = gridDim.x;
    const int bid = blockIdx.x;
    const int swz = (bid & 7) * (nwg >> 3) + (bid >> 3);
    const int ncol = N >> 7;
    const int trow = swz / ncol, tcol = swz % ncol;

    const int srow = wave * 8 + (lane >> 3);
    const int scol = ((lane & 7) ^ (lane >> 3)) * 8;
    const short* Abase = A + (size_t)(trow * 128 + srow) * K + scol;
    const short* Bbase = B + (size_t)(tcol * 128 + srow) * K + scol;
    short* AsBase = &As[wave * 8][0];
    short* BsBase = &Bs[wave * 8][0];

    const int rl = lane & 15;
    const int g0 = ((lane >> 4) ^ (lane & 7)) * 8;       // ks0 phys granule (shorts)
    const int g1 = ((4 + (lane >> 4)) ^ (lane & 7)) * 8; // ks1 phys granule

    f32x4 acc[4][4] = {};

    for (int kt = 0; kt < K; kt += 64) {
#pragma unroll
        for (int i = 0; i < 4; ++i) {
            gload_lds16(Abase + kt + (size_t)i * 32 * K, AsBase + i * 32 * 64);
            gload_lds16(Bbase + kt + (size_t)i * 32 * K, BsBase + i * 32 * 64);
        }
        __syncthreads();
#pragma unroll
        for (int ks = 0; ks < 2; ++ks) {
            const int g = ks ? g1 : g0;
            short8 af[4], bfr[4];
#pragma unroll
            for (int m = 0; m < 4; ++m)
                af[m] = *(const short8*)&As[wr * 64 + m * 16 + rl][g];
#pragma unroll
            for (int n = 0; n < 4; ++n)
                bfr[n] = *(const short8*)&Bs[wc * 64 + n * 16 + rl][g];
#pragma unroll
            for (int m = 0; m < 4; ++m)
#pragma unroll
                for (int n = 0; n < 4; ++n)
                    acc[m][n] = __builtin_amdgcn_mfma_f32_16x16x32_bf16(af[m], bfr[n], acc[m][n], 0, 0, 0);
        }
        __syncthreads();
    }

    // epilogue: C/D layout col = lane&15, row = (lane>>4)*4 + r
    const int crow0 = trow * 128 + wr * 64 + (lane >> 4) * 4;
    const int ccol0 = tcol * 128 + wc * 64 + rl;
#pragma unroll
    for (int n = 0; n < 4; ++n) {
        const int col = ccol0 + n * 16;
        const float bv = bias[col];
#pragma unroll
        for (int m = 0; m < 4; ++m) {
            const int row0 = crow0 + m * 16;
#pragma unroll
            for (int r = 0; r < 4; ++r) {
                float val = acc[m][n][r] + bv;
                if (OUT_BF16) Cb[(size_t)(row0 + r) * N + col] = f2b(val);
                else          Cf[(size_t)(row0 + r) * N + col] = val;
            }
        }
    }
}

// ---------- per-token cross-head attention, LDS-staged K/V (R9-proven best) ----------
// block = 256 thr / 16 tokens. Stage K+V (16 x 2048 shorts = 64 KB) with
// coalesced 16B loads; per-token rotation (col + 8*token mod 2048) puts the
// wave's 4 tokens on disjoint bank groups (reads are 16-lane broadcasts ->
// conflict-free). R14 showed V-from-global regresses (latency + 16x redundant
// line reads); K+V staging is the measured optimum (~60 us vs 40 us floor).
__global__ __launch_bounds__(256) void attn2(const short* __restrict__ qkv,
                                             short* __restrict__ out) {
    __shared__ short kv[16 * 2048];   // 64 KiB
    const int tid = threadIdx.x;
    const size_t t0 = (size_t)blockIdx.x * 16;

#pragma unroll
    for (int r = 0; r < 16; ++r) {
        short8 v = *(const short8*)(qkv + (t0 + r) * 3072 + 1024 + tid * 8);
        *(short8*)(kv + r * 2048 + ((tid * 8 + r * 8) & 2047)) = v;
    }
    __syncthreads();

    const int t = tid >> 4, h = tid & 15;
    const int rot = t * 8;
    const short* kt = kv + t * 2048;
    const short* q = qkv + (t0 + t) * 3072 + h * 64;

    float qf[64];
#pragma unroll
    for (int j = 0; j < 8; ++j) {
        short8 qv = *(const short8*)(q + j * 8);
#pragma unroll
        for (int i = 0; i < 8; ++i) qf[j * 8 + i] = b2f(qv[i]);
    }

    float s[16];
    float mx = -1e30f;
#pragma unroll
    for (int g = 0; g < 16; ++g) {
        float a = 0.f;
#pragma unroll
        for (int j = 0; j < 8; ++j) {
            short8 kvv = *(const short8*)(kt + ((g * 64 + j * 8 + rot) & 2047));
#pragma unroll
            for (int i = 0; i < 8; ++i) a += qf[j * 8 + i] * b2f(kvv[i]);
        }
        s[g] = a * 0.125f;   // scale = 1/sqrt(64)
        mx = fmaxf(mx, s[g]);
    }
    float den = 0.f;
#pragma unroll
    for (int g = 0; g < 16; ++g) { s[g] = __expf(s[g] - mx); den += s[g]; }
    float inv = 1.f / den;

#pragma unroll
    for (int j = 0; j < 8; ++j) {
        float o[8] = {0.f, 0.f, 0.f, 0.f, 0.f, 0.f, 0.f, 0.f};
#pragma unroll
        for (int g = 0; g < 16; ++g) {
            short8 vv = *(const short8*)(kt + ((1024 + g * 64 + j * 8 + rot) & 2047));
            float w = s[g];
#pragma unroll
            for (int i = 0; i < 8; ++i) o[i] += w * b2f(vv[i]);
        }
        short8 ov;
#pragma unroll
        for (int i = 0; i < 8; ++i) ov[i] = (short)f2b(o[i] * inv);
        *(short8*)(out + (t0 + t) * 1024 + h * 64 + j * 8) = ov;
    }
}

// ---------- launch ----------
extern "C" void kernel_launch(void* const* d_in, const int* in_sizes, int n_in,
                              void* d_out, int out_size, void* d_ws, size_t ws_size,
                              hipStream_t stream) {
    const float* x  = (const float*)d_in[0];
    const float* Wq = (const float*)d_in[1];
    const float* bq = (const float*)d_in[2];
    const float* Wk = (const float*)d_in[3];
    const float* bk = (const float*)d_in[4];
    const float* Wv = (const float*)d_in[5];
    const float* bv = (const float*)d_in[6];
    const float* Wo = (const float*)d_in[7];
    const float* bo = (const float*)d_in[8];
    float* out = (float*)d_out;

    const int N = 32768, E = 1024;

    char* ws = (char*)d_ws;
    size_t off = 0;
    short* xb = (short*)(ws + off);         off += (size_t)N * E * 2;
    short* wqkv = (short*)(ws + off);       off += (size_t)3 * E * E * 2;
    short* wo = (short*)(ws + off);         off += (size_t)E * E * 2;
    float* bqkv = (float*)(ws + off);       off += (size_t)3 * E * 4;
    off = (off + 255) & ~(size_t)255;
    short* y1 = (short*)(ws + off);         off += (size_t)N * 3 * E * 2;
    short* ao = xb;  // reuse xb: dead after GEMM1

    // 1) fused conversion (single launch)
    cvt_all<<<dim3(18433), dim3(256), 0, stream>>>(
        x, Wq, Wk, Wv, Wo, bq, bk, bv,
        (unsigned short*)xb, (unsigned short*)wqkv, (unsigned short*)wo, bqkv);

    // 2) QKV projection: grid (32768/128)*(3072/128) = 256*24 = 6144 (%8==0)
    gemm128<true><<<dim3((N / 128) * (3 * E / 128)), dim3(256), 0, stream>>>(
        xb, wqkv, bqkv, (unsigned short*)y1, nullptr, N, 3 * E, E);

    // 3) per-token attention, K+V LDS-staged: 2048 blocks x 256 thr
    attn2<<<dim3(N / 16), dim3(256), 0, stream>>>(y1, ao);

    // 4) output projection: grid 256*8 = 2048 (%8==0)
    gemm128<false><<<dim3((N / 128) * (E / 128)), dim3(256), 0, stream>>>(
        ao, wo, bo, nullptr, out, N, E, E);
}